// Round 9
// baseline (35.286 us; speedup 1.0000x reference)
//
#include <hip/hip_runtime.h>
#include <hip/hip_bf16.h>
#include <math.h>

// ThickCubeSimulator R8: single-kernel, zero-workspace version.
//  R7 post-mortem: matvec was cheap all along; residual = deposit (~20us) +
//  2-kernel launch/dependency overhead (~4-6us) + small phases.
//  R8 removes ALL non-deposit structure: Gaussian weights computed on the fly
//  inside the b-sliced matvec (160 exp2/lane ~= 1.7us chip), params derived
//  per-thread. Deposit is BIT-IDENTICAL to R7 for clean attribution.

#define RES   80
#define NB    160
#define NBP   161
#define NM    40
#define H4P   164        // padded per-pixel H stride (16B-aligned b128 reads)
#define NPIXT (RES*RES)
#define NPIXB 4          // coarse pixels per block
#define C_KMS 299792.458f
#define F0GHZ 230.538f
#define LOG2E 1.44269504088896340736f
#define HPI   1.57079632679489662f
#define VBIN0 -198.75f
#define VBINW 2.5f

__device__ __forceinline__ float fast_exp2(float x) {
#if __has_builtin(__builtin_amdgcn_exp2f)
  return __builtin_amdgcn_exp2f(x);
#else
  return exp2f(x);
#endif
}
__device__ __forceinline__ float fast_rcp(float x) {
#if __has_builtin(__builtin_amdgcn_rcpf)
  return __builtin_amdgcn_rcpf(x);
#else
  return 1.0f / x;
#endif
}

// atan(u) for u>=0 via t=min(u,1/u) in [0,1], poly err ~1e-6 rad
__device__ __forceinline__ float atan_pos(float u, float uinv) {
  const float t  = fminf(u, uinv);
  const float t2 = t * t;
  float p = fmaf(t2, -0.0117212f, 0.05265332f);
  p = fmaf(t2, p, -0.11643287f);
  p = fmaf(t2, p, 0.19354346f);
  p = fmaf(t2, p, -0.33262347f);
  p = fmaf(t2, p, 0.99997726f);
  const float a = t * p;
  return (u <= 1.0f) ? a : (HPI - a);
}

// per-cell math -> (UO = bin coordinate, IO = intensity); independent chain
#define CELL(kk, UO, IO) {                                  \
    const float gz = -993.75f + 12.5f * (float)(kk);        \
    const float ry = fmaf(-si, gz, y1ci);                   \
    const float s2 = fmaf(ry, ry, x12);                     \
    const float rq = sqrtf(s2);                             \
    const float ri = fast_rcp(fmaxf(rq, 1e-30f));           \
    const float at = atan_pos(rq * irt, rt * ri);           \
    const float rs = sqrtf(fmaf(gz, gz, gxy2));             \
    UO = fmaf(kcol * (ri * at), invw, boff);                \
    IO = fast_exp2(fmaf(rs, crd, li0)); }

// run-length CIC merge of one (uu, inten) into (cb, a0, a1); flush on change
#define MERGE(uu, inten) {                                  \
    const int   bi = (int)(uu);                             \
    const float w1 = (inten) * ((uu) - (float)bi);          \
    const float w0 = (inten) - w1;                          \
    if (bi == cb)          { a0 += w0; a1 += w1; }          \
    else if (bi == cb + 1) { unsafeAtomicAdd(&Hc[cb], a0);  \
                             a0 = a1 + w0; a1 = w1; cb = bi; } \
    else { unsafeAtomicAdd(&Hc[cb], a0);                    \
           unsafeAtomicAdd(&Hc[cb + 1], a1);                \
           a0 = w0; a1 = w1; cb = bi; } }

__global__ __launch_bounds__(256, 6) void fused_kernel(
    const float* __restrict__ p_inc, const float* __restrict__ p_rot,
    const float* __restrict__ p_lb,  const float* __restrict__ p_vs,
    const float* __restrict__ p_vmax, const float* __restrict__ p_rturn,
    const float* __restrict__ p_i0,  const float* __restrict__ p_rd,
    const float* __restrict__ freqs, float* __restrict__ out)
{
  __shared__ float Hs[16 * NBP];                  // 16 sub-hists, 10304 B
  __shared__ __align__(16) float H4[NPIXB * H4P]; // per-pixel hists, 2624 B
  __shared__ float Pp[16 * NM];                   // [w*4+pix][m], 2560 B

  const int t   = threadIdx.x;
  const int blk = blockIdx.x;                     // 0..1599
  const int p   = blk / (RES / NPIXB);
  const int q0  = (blk - p * (RES / NPIXB)) * NPIXB;

  // per-thread parameter derivation (scalar broadcast loads + ~8 trans ops)
  const float inc = p_inc[0], rotv = p_rot[0], sig = p_lb[0];
  const float si = sinf(inc), ci = cosf(inc);
  const float cr = cosf(rotv), sr = sinf(rotv);
  const float kfac = -p_vmax[0] * 0.63661977236758134f * si;
  const float rt   = p_rturn[0];
  const float irt  = 1.0f / rt;
  const float crd  = -LOG2E / p_rd[0];
  const float li0  = __log2f(p_i0[0]);
  const float invw = 1.0f / VBINW;
  const float boff = -VBIN0 / VBINW;
  const float c2l    = -0.5f * LOG2E / (sig * sig);
  const float norm16 = 0.3989422804014327f / sig * 0.0625f;
  const float df     = (freqs[1] - freqs[0]) * 0.25f;
  const float f0     = freqs[0] - 1.5f * df;
  const float vshift = p_vs[0];

  for (int e = t; e < 16 * NBP; e += 256) Hs[e] = 0.f;
  __syncthreads();

  // ---- deposit: wave = pixel, 4 cols x 16 segments x 10 consecutive z ----
  // (bit-identical to R7 for attribution)
  {
    const int pix = t >> 6;          // 0..3 (wave-uniform)
    const int col = (t >> 4) & 3;    // fine 2x2 pixel
    const int seg = t & 15;          // 10-z segment
    const int i   = 2 * p + (col >> 1);
    const int j   = 2 * (q0 + pix) + (col & 1);
    const float gx = -993.75f + 12.5f * (float)i;
    const float gy = -993.75f + 12.5f * (float)j;
    const float x1 = gx * cr - gy * sr;
    const float y1 = gx * sr + gy * cr;
    const float x12  = x1 * x1;
    const float gxy2 = gx * gx + gy * gy;
    const float y1ci = y1 * ci;
    const float kcol = kfac * x1;
    float* Hc = &Hs[(pix * 4 + col) * NBP];

    const int k0 = seg * 10;
    float U[5], I[5];
    int cb; float a0, a1;
    #pragma unroll
    for (int c = 0; c < 5; ++c) CELL(k0 + c, U[c], I[c])       // batch 1: ILP
    { const int bi = (int)U[0];
      const float w1 = I[0] * (U[0] - (float)bi);
      cb = bi; a0 = I[0] - w1; a1 = w1; }
    #pragma unroll
    for (int c = 1; c < 5; ++c) MERGE(U[c], I[c])
    #pragma unroll
    for (int c = 0; c < 5; ++c) CELL(k0 + 5 + c, U[c], I[c])   // batch 2: ILP
    #pragma unroll
    for (int c = 0; c < 5; ++c) MERGE(U[c], I[c])
    unsafeAtomicAdd(&Hc[cb],     a0);
    unsafeAtomicAdd(&Hc[cb + 1], a1);
  }
  __syncthreads();

  // ---- reduce 4 sub-hists -> per-pixel histogram (padded stride) ----
  for (int e = t; e < NPIXB * NB; e += 256) {
    const int v = e / NB;
    const int b = e - v * NB;
    H4[v * H4P + b] = (Hs[(v * 4 + 0) * NBP + b] + Hs[(v * 4 + 1) * NBP + b])
                    + (Hs[(v * 4 + 2) * NBP + b] + Hs[(v * 4 + 3) * NBP + b]);
  }
  __syncthreads();

  // ---- matvec with on-the-fly Gaussian weights ----
  // wave w owns bin slice [40w, 40w+40) for ALL 4 pixels; lane = channel m.
  // g(b,m) = sum_r exp2(c2l*(vlab[4m+r]-vbin_b)^2) computed in-registers:
  // 160 exp2 per lane, no GT table anywhere.
  {
    const int w = t >> 6;
    const int l = t & 63;
    if (l < NM) {
      float vlab[4];
      #pragma unroll
      for (int r = 0; r < 4; ++r) {
        const float ffine = f0 + df * (float)(4 * l + r);
        vlab[r] = C_KMS * (F0GHZ - ffine) / F0GHZ - vshift;
      }
      float acc[NPIXB] = {0.f, 0.f, 0.f, 0.f};
      const int b0w = w * 40;
      #pragma unroll 2
      for (int c4 = 0; c4 < 10; ++c4) {
        const int b0 = b0w + c4 * 4;
        float g[4];
        #pragma unroll
        for (int s = 0; s < 4; ++s) {
          const float vbin = VBIN0 + VBINW * (float)(b0 + s);
          float sg = 0.f;
          #pragma unroll
          for (int r = 0; r < 4; ++r) {
            const float d = vlab[r] - vbin;
            sg += fast_exp2(c2l * d * d);
          }
          g[s] = sg;
        }
        #pragma unroll
        for (int pix = 0; pix < NPIXB; ++pix) {
          const float4 h = *(const float4*)&H4[pix * H4P + b0];
          acc[pix] = fmaf(h.x, g[0], fmaf(h.y, g[1],
                     fmaf(h.z, g[2], fmaf(h.w, g[3], acc[pix]))));
        }
      }
      #pragma unroll
      for (int pix = 0; pix < NPIXB; ++pix)
        Pp[(w * NPIXB + pix) * NM + l] = acc[pix] * norm16;
    }
  }
  __syncthreads();

  if (t < NPIXB * NM) {
    const int m   = t >> 2;
    const int pix = t & 3;
    const float s = (Pp[(0 * NPIXB + pix) * NM + m] +
                     Pp[(1 * NPIXB + pix) * NM + m]) +
                    (Pp[(2 * NPIXB + pix) * NM + m] +
                     Pp[(3 * NPIXB + pix) * NM + m]);
    out[(size_t)m * NPIXT + p * RES + q0 + pix] = s;
  }
}

extern "C" void kernel_launch(void* const* d_in, const int* in_sizes, int n_in,
                              void* d_out, int out_size, void* d_ws, size_t ws_size,
                              hipStream_t stream) {
  const float* p_inc   = (const float*)d_in[0];
  const float* p_rot   = (const float*)d_in[1];
  const float* p_lb    = (const float*)d_in[2];
  const float* p_vs    = (const float*)d_in[3];
  const float* p_vmax  = (const float*)d_in[4];
  const float* p_rturn = (const float*)d_in[5];
  const float* p_i0    = (const float*)d_in[6];
  const float* p_rd    = (const float*)d_in[7];
  const float* freqs   = (const float*)d_in[8];
  float* out = (float*)d_out;

  hipLaunchKernelGGL(fused_kernel, dim3(NPIXT / NPIXB), dim3(256),
                     0, stream, p_inc, p_rot, p_lb, p_vs, p_vmax, p_rturn,
                     p_i0, p_rd, freqs, out);
}